// Round 12
// baseline (220.897 us; speedup 1.0000x reference)
//
#include <hip/hip_runtime.h>
#include <math.h>

// Problem constants (fixed by the reference setup)
#define NTOT 32768
#define NB   64
#define NPB  512      // rows per segment
#define DQK  128
#define MF   256      // feature count m
#define DVV  256      // value dim

#define QK_SCALE   0.29730177875068026f   // 128^-0.25
#define INV_SQRT_M 0.0625f                // 1/sqrt(256)
#define EPS_PHI    1e-4f
#define EPS_NORM   1e-8f
#define EPS_ISM    (EPS_PHI * INV_SQRT_M)

typedef float f32x4  __attribute__((ext_vector_type(4)));
typedef short bf16x8 __attribute__((ext_vector_type(8)));
typedef unsigned short us4 __attribute__((ext_vector_type(4)));
typedef unsigned short us8 __attribute__((ext_vector_type(8)));

static __device__ __forceinline__ float red_max32(float v) {
    v = fmaxf(v, __shfl_xor(v, 1, 64));
    v = fmaxf(v, __shfl_xor(v, 2, 64));
    v = fmaxf(v, __shfl_xor(v, 4, 64));
    v = fmaxf(v, __shfl_xor(v, 8, 64));
    v = fmaxf(v, __shfl_xor(v, 16, 64));
    return v;
}
static __device__ __forceinline__ float red_sum16(float v) {
    v += __shfl_xor(v, 1, 64);
    v += __shfl_xor(v, 2, 64);
    v += __shfl_xor(v, 4, 64);
    v += __shfl_xor(v, 8, 64);
    return v;
}
static __device__ __forceinline__ float red_max16(float v) {
    v = fmaxf(v, __shfl_xor(v, 1, 64));
    v = fmaxf(v, __shfl_xor(v, 2, 64));
    v = fmaxf(v, __shfl_xor(v, 4, 64));
    v = fmaxf(v, __shfl_xor(v, 8, 64));
    return v;
}

// split f32 into bf16 hi + bf16 lo (RNE both): hi+lo ~ x to ~2^-17 rel.
static __device__ __forceinline__ void bfsplit(float x, unsigned short& h, unsigned short& l) {
    unsigned u = __float_as_uint(x);
    unsigned r = (u + 0x7fffu + ((u >> 16) & 1u)) & 0xffff0000u;
    h = (unsigned short)(r >> 16);
    float lo = x - __uint_as_float(r);
    unsigned v = __float_as_uint(lo);
    l = (unsigned short)((v + 0x7fffu + ((v >> 16) & 1u)) >> 16);
}

// ---------------------------------------------------------------------------
// Kernel 0: omega -> FRAGMENT-ORDERED bf16 hi/lo (unchanged from r11).
// ---------------------------------------------------------------------------
__global__ __launch_bounds__(256) void omsplit_kernel(
    const float* __restrict__ omega,
    unsigned short* __restrict__ OmFh, unsigned short* __restrict__ OmFl)
{
    const int k = blockIdx.x;      // 0..127
    const int m = threadIdx.x;     // 0..255
    unsigned short h, l;
    bfsplit(omega[k * MF + m], h, l);
    const int M16 = m >> 4, fr = m & 15;
    const int c = k >> 5, kk = k & 31;
    const int lane = fr + 16 * (kk >> 3);
    const size_t idx = ((size_t)(M16 * 4 + c) * 64 + lane) * 8 + (kk & 7);
    OmFh[idx] = h;
    OmFl[idx] = l;
}

// ---------------------------------------------------------------------------
// Kernel 1 (MFMA): U = (X * d^-1/4) @ omega  (unchanged from r11).
//   IS_QUERY: outH/outL = bf16 split of Qp; aux = norm.
//   else:     outF = exp(U-h-rowmax) f32; aux = rowmax.
// ---------------------------------------------------------------------------
template <bool IS_QUERY>
__global__ __launch_bounds__(256) void phi_kernel(
    const float* __restrict__ X,
    const unsigned short* __restrict__ OmFh, const unsigned short* __restrict__ OmFl,
    const float* __restrict__ Ksum,
    float* __restrict__ outF,
    unsigned short* __restrict__ outH, unsigned short* __restrict__ outL,
    float* __restrict__ aux)
{
    __shared__ __align__(16) float Xf[64][132];
    __shared__ float hS[64];
    __shared__ float mxW[4][64];
    __shared__ float npW[4][64];
    __shared__ float KsS[256];

    const int tid  = threadIdx.x;
    const int lane = tid & 63;
    const int w    = tid >> 6;        // wave = m-quadrant 0..3
    const int fr   = lane & 15;
    const int k8   = (lane >> 4) * 8;
    const int rg   = (lane >> 4) * 4;
    const int row0 = blockIdx.x * 64;

    if (IS_QUERY) KsS[tid] = Ksum[(row0 >> 9) * MF + tid];

    // ---- stage X (scaled, natural [row][k]) + exact f32 h partials ----
    float hp[8];
    {
        const float4* Xv = (const float4*)(X + (size_t)row0 * DQK);
        #pragma unroll
        for (int j = 0; j < 8; ++j) {
            int idx = tid + 256 * j;
            int r = idx >> 5, c4 = idx & 31;
            float4 v = Xv[idx];
            v.x *= QK_SCALE; v.y *= QK_SCALE; v.z *= QK_SCALE; v.w *= QK_SCALE;
            *(float4*)&Xf[r][c4 * 4] = v;
            hp[j] = v.x * v.x + v.y * v.y + v.z * v.z + v.w * v.w;
        }
    }
    __syncthreads();
    #pragma unroll
    for (int j = 0; j < 8; ++j) {
        hp[j] += __shfl_xor(hp[j], 1, 64);
        hp[j] += __shfl_xor(hp[j], 2, 64);
        hp[j] += __shfl_xor(hp[j], 4, 64);
        hp[j] += __shfl_xor(hp[j], 8, 64);
        hp[j] += __shfl_xor(hp[j], 16, 64);
    }
    if ((tid & 31) == 0) {
        #pragma unroll
        for (int j = 0; j < 8; ++j) hS[(tid >> 5) + 8 * j] = hp[j];
    }

    // ---- MFMA main loop (no barriers: Xf read-only, B from global) ----
    f32x4 acc[4][4] = {};    // [row-tile t][col-tile u]
    #pragma unroll
    for (int c = 0; c < 4; ++c) {
        bf16x8 ah[4], al[4];
        #pragma unroll
        for (int t = 0; t < 4; ++t) {
            float a[8];
            *(float4*)&a[0] = *(const float4*)&Xf[t * 16 + fr][c * 32 + k8];
            *(float4*)&a[4] = *(const float4*)&Xf[t * 16 + fr][c * 32 + k8 + 4];
            unsigned short hh[8], ll[8];
            #pragma unroll
            for (int s = 0; s < 8; ++s) bfsplit(a[s], hh[s], ll[s]);
            ah[t] = *(bf16x8*)&hh[0];
            al[t] = *(bf16x8*)&ll[0];
        }
        #pragma unroll
        for (int u = 0; u < 4; ++u) {
            const size_t ob = ((size_t)((w * 4 + u) * 4 + c) * 64 + lane) * 8;
            bf16x8 bh = *(const bf16x8*)&OmFh[ob];
            bf16x8 bl = *(const bf16x8*)&OmFl[ob];
            #pragma unroll
            for (int t = 0; t < 4; ++t) {
                acc[t][u] = __builtin_amdgcn_mfma_f32_16x16x32_bf16(ah[t], bh, acc[t][u], 0, 0, 0);
                acc[t][u] = __builtin_amdgcn_mfma_f32_16x16x32_bf16(ah[t], bl, acc[t][u], 0, 0, 0);
                acc[t][u] = __builtin_amdgcn_mfma_f32_16x16x32_bf16(al[t], bh, acc[t][u], 0, 0, 0);
            }
        }
    }

    // ---- rowmax: per-lane over u, reduce over fr lanes, cross-wave LDS ----
    #pragma unroll
    for (int t = 0; t < 4; ++t) {
        #pragma unroll
        for (int g = 0; g < 4; ++g) {
            float m0 = fmaxf(fmaxf(acc[t][0][g], acc[t][1][g]),
                             fmaxf(acc[t][2][g], acc[t][3][g]));
            m0 = red_max16(m0);
            if (fr == 0) mxW[w][t * 16 + rg + g] = m0;
        }
    }
    __syncthreads();

    // ---- epilogue ----
    #pragma unroll
    for (int t = 0; t < 4; ++t) {
        #pragma unroll
        for (int g = 0; g < 4; ++g) {
            const int row  = t * 16 + rg + g;
            const int grow = row0 + row;
            const float mxa = fmaxf(fmaxf(mxW[0][row], mxW[1][row]),
                                    fmaxf(mxW[2][row], mxW[3][row]));
            const float hm = 0.5f * hS[row] + mxa;
            if (IS_QUERY) {
                float np = 0.f;
                #pragma unroll
                for (int u = 0; u < 4; ++u) {
                    const int col = w * 64 + u * 16 + fr;
                    const float q = (__expf(acc[t][u][g] - hm) + EPS_PHI) * INV_SQRT_M;
                    unsigned short qh, ql;
                    bfsplit(q, qh, ql);
                    outH[(size_t)grow * MF + col] = qh;
                    outL[(size_t)grow * MF + col] = ql;
                    np = fmaf(q, KsS[col], np);
                }
                np = red_sum16(np);
                if (fr == 0) npW[w][row] = np;
            } else {
                #pragma unroll
                for (int u = 0; u < 4; ++u)
                    outF[(size_t)grow * MF + w * 64 + u * 16 + fr] = __expf(acc[t][u][g] - hm);
                if (w == 0 && fr == 0) aux[grow] = mxa;
            }
        }
    }
    if (IS_QUERY) {
        __syncthreads();
        if (w == 0 && fr == 0) {
            #pragma unroll
            for (int t = 0; t < 4; ++t)
                #pragma unroll
                for (int g = 0; g < 4; ++g) {
                    const int row = t * 16 + rg + g;
                    aux[row0 + row] = npW[0][row] + npW[1][row] + npW[2][row] + npW[3][row];
                }
        }
    }
}

// ---------------------------------------------------------------------------
// Kernel 2: sexp[n] = exp(rmax[n] - max_{segment} rmax)  (unchanged)
// ---------------------------------------------------------------------------
__global__ __launch_bounds__(256) void segsexp_kernel(
    const float* __restrict__ rmax, float* __restrict__ sexp)
{
    const int b = blockIdx.x, tid = threadIdx.x;
    const float r0 = rmax[b * NPB + tid];
    const float r1 = rmax[b * NPB + 256 + tid];
    float v = fmaxf(r0, r1);
    v = red_max32(v);
    v = fmaxf(v, __shfl_xor(v, 32, 64));
    __shared__ float red[4];
    if ((tid & 63) == 0) red[tid >> 6] = v;
    __syncthreads();
    const float smax = fmaxf(fmaxf(red[0], red[1]), fmaxf(red[2], red[3]));
    sexp[b * NPB + tid]       = __expf(r0 - smax);
    sexp[b * NPB + 256 + tid] = __expf(r1 - smax);
}

// ---------------------------------------------------------------------------
// Kernel 3 (MFMA): KV partial over 256 n, 2-way split (unchanged from r11).
// ---------------------------------------------------------------------------
__global__ __launch_bounds__(256) void kv_kernel(
    const float* __restrict__ A, const float* __restrict__ V,
    const float* __restrict__ sexp,
    float* __restrict__ KV, float* __restrict__ P1,
    float* __restrict__ Ksum, float* __restrict__ KsumP)
{
    __shared__ __align__(16) float Af[32][132];
    __shared__ __align__(16) float Vf[32][132];
    __shared__ __align__(16) unsigned short KpH[128][40];
    __shared__ __align__(16) unsigned short KpL[128][40];
    __shared__ __align__(16) unsigned short VH[128][40];
    __shared__ __align__(16) unsigned short VL[128][40];

    const int tid  = threadIdx.x;
    const int lane = tid & 63;
    const int w    = tid >> 6;
    const int wr   = w >> 1;          // m-quadrant
    const int wc   = w & 1;           // v-quadrant
    const int fr   = lane & 15;
    const int k8   = (lane >> 4) * 8;
    const int rg   = (lane >> 4) * 4;

    const int vt = blockIdx.x, mt = blockIdx.y;
    const int b  = blockIdx.z >> 1, ch = blockIdx.z & 1;
    const int m0 = mt * 128, v0 = vt * 128;
    const size_t n0 = (size_t)b * NPB + ch * 256;

    const int ln  = tid >> 5;     // staging n row (+8j)
    const int lm4 = tid & 31;     // staging float4 col
    const int tv  = tid >> 1;     // transpose-pass output row (m or v)
    const int th  = tid & 1;      // transpose-pass n-half

    f32x4 acc[4][4] = {};
    float4 ks4 = {0.f, 0.f, 0.f, 0.f};

    for (int c = 0; c < 8; ++c) {
        __syncthreads();
        // ---- phase A: global -> f32 bounces (+ exact Ksum partials) ----
        #pragma unroll
        for (int j = 0; j < 4; ++j) {
            const size_t n = n0 + c * 32 + ln + 8 * j;
            float4 a  = *(const float4*)&A[n * MF + m0 + lm4 * 4];
            float4 vv = *(const float4*)&V[n * DVV + v0 + lm4 * 4];
            const float s2 = sexp[n] * INV_SQRT_M;
            float4 e;
            e.x = fmaf(a.x, s2, EPS_ISM);
            e.y = fmaf(a.y, s2, EPS_ISM);
            e.z = fmaf(a.z, s2, EPS_ISM);
            e.w = fmaf(a.w, s2, EPS_ISM);
            ks4.x += e.x; ks4.y += e.y; ks4.z += e.z; ks4.w += e.w;
            *(float4*)&Af[ln + 8 * j][lm4 * 4] = e;
            *(float4*)&Vf[ln + 8 * j][lm4 * 4] = vv;
        }
        __syncthreads();
        // ---- phase B: transpose-read + bfsplit -> bf16 [idx][n] tiles ----
        {
            unsigned short hh[16], ll[16];
            #pragma unroll
            for (int s = 0; s < 16; ++s)
                bfsplit(Af[th * 16 + s][tv], hh[s], ll[s]);
            *(us8*)&KpH[tv][th * 16]     = *(us8*)&hh[0];
            *(us8*)&KpH[tv][th * 16 + 8] = *(us8*)&hh[8];
            *(us8*)&KpL[tv][th * 16]     = *(us8*)&ll[0];
            *(us8*)&KpL[tv][th * 16 + 8] = *(us8*)&ll[8];
            #pragma unroll
            for (int s = 0; s < 16; ++s)
                bfsplit(Vf[th * 16 + s][tv], hh[s], ll[s]);
            *(us8*)&VH[tv][th * 16]     = *(us8*)&hh[0];
            *(us8*)&VH[tv][th * 16 + 8] = *(us8*)&hh[8];
            *(us8*)&VL[tv][th * 16]     = *(us8*)&ll[0];
            *(us8*)&VL[tv][th * 16 + 8] = *(us8*)&ll[8];
        }
        __syncthreads();
        // ---- MFMA: 16 tiles x 3 split terms ----
        bf16x8 ah[4], al[4];
        #pragma unroll
        for (int t = 0; t < 4; ++t) {
            ah[t] = *(const bf16x8*)&KpH[wr * 64 + t * 16 + fr][k8];
            al[t] = *(const bf16x8*)&KpL[wr * 64 + t * 16 + fr][k8];
        }
        #pragma unroll
        for (int u = 0; u < 4; ++u) {
            bf16x8 bh = *(const bf16x8*)&VH[wc * 64 + u * 16 + fr][k8];
            bf16x8 bl = *(const bf16x8*)&VL[wc * 64 + u * 16 + fr][k8];
            #pragma unroll
            for (int t = 0; t < 4; ++t) {
                acc[t][u] = __builtin_amdgcn_mfma_f32_16x16x32_bf16(ah[t], bh, acc[t][u], 0, 0, 0);
                acc[t][u] = __builtin_amdgcn_mfma_f32_16x16x32_bf16(ah[t], bl, acc[t][u], 0, 0, 0);
                acc[t][u] = __builtin_amdgcn_mfma_f32_16x16x32_bf16(al[t], bh, acc[t][u], 0, 0, 0);
            }
        }
    }

    // ---- store partial tile ----
    float* __restrict__ dKV = ch ? P1 : KV;
    #pragma unroll
    for (int t = 0; t < 4; ++t) {
        #pragma unroll
        for (int g = 0; g < 4; ++g) {
            const int row = wr * 64 + t * 16 + rg + g;
            const size_t base = ((size_t)b * MF + m0 + row) * DVV + v0 + wc * 64;
            #pragma unroll
            for (int u = 0; u < 4; ++u)
                dKV[base + u * 16 + fr] = acc[t][u][g];
        }
    }

    // ---- Ksum: exact-f32 per-thread partials -> LDS scratch -> reduce ----
    if (vt == 0) {
        __syncthreads();                       // bounce reads done
        float* scr = &Af[0][0];                // flat [8][128]
        *(float4*)&scr[(ln * 32 + lm4) * 4] = ks4;
        __syncthreads();
        if (tid < 128) {
            float s = 0.f;
            #pragma unroll
            for (int g = 0; g < 8; ++g) s += scr[g * 128 + tid];
            (ch ? KsumP : Ksum)[b * MF + m0 + tid] = s;
        }
    }
}

// ---------------------------------------------------------------------------
// Kernel 3b (r12, replaces kvreduce): fold KV+P1, TRANSPOSE, bf16-split,
// and emit in out_kernel's B-fragment order:
//   KVF[(((b*16+V16)*8 + c)*64 + l)*8 + e] = bf16(KVfold[b][m][v]),
//   v = V16*16 + (l&15), m = c*32 + (l>>4)*8 + e.
// Also folds Ksum += KsumP (V16==0 blocks). Output lives in the dead A
// buffer (A fully consumed by kv). One block per (V16, b); 20.5 KB LDS.
// ---------------------------------------------------------------------------
__global__ __launch_bounds__(256) void kvsplit_kernel(
    const float* __restrict__ KV, const float* __restrict__ P1,
    unsigned short* __restrict__ KVFh, unsigned short* __restrict__ KVFl,
    float* __restrict__ Ksum, const float* __restrict__ KsumP)
{
    __shared__ __align__(16) float T[256][20];

    const int V16 = blockIdx.x;   // 0..15
    const int b   = blockIdx.y;   // 0..63
    const int tid = threadIdx.x;  // staging row m

    {
        const size_t base = ((size_t)b * MF + tid) * DVV + V16 * 16;
        #pragma unroll
        for (int q = 0; q < 4; ++q) {
            float4 a = *(const float4*)&KV[base + q * 4];
            float4 p = *(const float4*)&P1[base + q * 4];
            a.x += p.x; a.y += p.y; a.z += p.z; a.w += p.w;
            *(float4*)&T[tid][q * 4] = a;
        }
    }
    if (V16 == 0)
        Ksum[b * MF + tid] += KsumP[b * MF + tid];
    __syncthreads();

    const int l  = tid & 63;
    const int fr = l & 15;
    const int s  = l >> 4;
    const int c0 = tid >> 6;      // 0..3
    #pragma unroll
    for (int cc = 0; cc < 2; ++cc) {
        const int c = c0 + cc * 4;
        unsigned short hh[8], ll[8];
        #pragma unroll
        for (int e = 0; e < 8; ++e)
            bfsplit(T[c * 32 + s * 8 + e][fr], hh[e], ll[e]);
        const size_t idx = ((((size_t)b * 16 + V16) * 8 + c) * 64 + l) * 8;
        *(us8*)&KVFh[idx] = *(us8*)&hh[0];
        *(us8*)&KVFl[idx] = *(us8*)&ll[0];
    }
}

// ---------------------------------------------------------------------------
// Kernel 4 (r12): out = (Qp @ KV[b]) / (norm + eps), bf16-split MFMA.
// Both operands pre-split: Q from QpH/QpL (LDS-staged us4 copies), KV
// DIRECT from global in fragment order (KVFh/KVFl — coalesced 1KB/wave,
// L2-resident per b). 64-row tiles -> grid (2,8,64)=1024 = 4 blocks/CU;
// acc 2x4 tiles (32 regs); LDS 10.5 KB; 2 barriers/chunk, no bfsplit.
// ---------------------------------------------------------------------------
__global__ __launch_bounds__(256) void out_kernel(
    const unsigned short* __restrict__ QpH, const unsigned short* __restrict__ QpL,
    const unsigned short* __restrict__ KVFh, const unsigned short* __restrict__ KVFl,
    const float* __restrict__ normv, float* __restrict__ out)
{
    __shared__ __align__(16) unsigned short Qh[64][40];
    __shared__ __align__(16) unsigned short Ql[64][40];
    __shared__ float nrmS[64];

    const int tid  = threadIdx.x;
    const int lane = tid & 63;
    const int w    = tid >> 6;
    const int wr   = w >> 1;          // row half (32 rows)
    const int wc   = w & 1;           // v half (64 cols)
    const int fr   = lane & 15;
    const int k8   = (lane >> 4) * 8;

    const int vt = blockIdx.x, rt = blockIdx.y, b = blockIdx.z;
    const int v0 = vt * 128;
    const int r0 = b * NPB + rt * 64;

    if (tid < 64) nrmS[tid] = normv[r0 + tid];

    const int qr  = tid >> 3;     // 0..31 (+32)
    const int qm4 = tid & 7;

    f32x4 acc[2][4] = {};

    for (int c = 0; c < 8; ++c) {
        const int mc = c * 32;
        __syncthreads();
        #pragma unroll
        for (int j = 0; j < 2; ++j) {
            const size_t qb = (size_t)(r0 + qr + 32 * j) * MF + mc + qm4 * 4;
            *(us4*)&Qh[qr + 32 * j][qm4 * 4] = *(const us4*)&QpH[qb];
            *(us4*)&Ql[qr + 32 * j][qm4 * 4] = *(const us4*)&QpL[qb];
        }
        __syncthreads();
        bf16x8 ah[2], al[2];
        #pragma unroll
        for (int t = 0; t < 2; ++t) {
            ah[t] = *(const bf16x8*)&Qh[wr * 32 + t * 16 + fr][k8];
            al[t] = *(const bf16x8*)&Ql[wr * 32 + t * 16 + fr][k8];
        }
        #pragma unroll
        for (int u = 0; u < 4; ++u) {
            const size_t kb = ((((size_t)b * 16 + vt * 8 + wc * 4 + u) * 8 + c) * 64 + lane) * 8;
            bf16x8 bh = *(const bf16x8*)&KVFh[kb];
            bf16x8 bl = *(const bf16x8*)&KVFl[kb];
            #pragma unroll
            for (int t = 0; t < 2; ++t) {
                acc[t][u] = __builtin_amdgcn_mfma_f32_16x16x32_bf16(ah[t], bh, acc[t][u], 0, 0, 0);
                acc[t][u] = __builtin_amdgcn_mfma_f32_16x16x32_bf16(ah[t], bl, acc[t][u], 0, 0, 0);
                acc[t][u] = __builtin_amdgcn_mfma_f32_16x16x32_bf16(al[t], bh, acc[t][u], 0, 0, 0);
            }
        }
    }

    const int rg = (lane >> 4) * 4;
    #pragma unroll
    for (int t = 0; t < 2; ++t) {
        #pragma unroll
        for (int g = 0; g < 4; ++g) {
            const int row = wr * 32 + t * 16 + rg + g;
            const float inv = 1.0f / (nrmS[row] + EPS_NORM);
            const size_t base = (size_t)(r0 + row) * DVV + v0 + wc * 64;
            #pragma unroll
            for (int u = 0; u < 4; ++u)
                out[base + u * 16 + fr] = acc[t][u][g] * inv;
        }
    }
}

// ---------------------------------------------------------------------------
extern "C" void kernel_launch(void* const* d_in, const int* in_sizes, int n_in,
                              void* d_out, int out_size, void* d_ws, size_t ws_size,
                              hipStream_t stream)
{
    const float* Q     = (const float*)d_in[0];
    const float* K     = (const float*)d_in[1];
    const float* V     = (const float*)d_in[2];
    const float* omega = (const float*)d_in[3];
    float* out = (float*)d_out;

    float* ws    = (float*)d_ws;
    float* Qp    = ws;                              // N*M: P1 during kv; QpH/QpL after phi_Q
    float* A     = Qp    + (size_t)NTOT * MF;       // N*M: A' f32; KVFh/KVFl after kv
    float* KV    = A     + (size_t)NTOT * MF;       // B*M*DV
    float* Ksum  = KV    + (size_t)NB * MF * DVV;   // B*M
    float* KsumP = Ksum  + (size_t)NB * MF;         // B*M
    float* rmaxA = KsumP + (size_t)NB * MF;         // N
    float* sexp  = rmaxA + NTOT;                    // N
    float* normv = sexp  + NTOT;                    // N
    unsigned short* OmFh = (unsigned short*)(normv + NTOT);   // MF*DQK us
    unsigned short* OmFl = OmFh + (size_t)MF * DQK;           // MF*DQK us

    float* P1 = Qp;                                 // f32 partial; dead before phi_Q
    unsigned short* QpH = (unsigned short*)Qp;                // N*M us
    unsigned short* QpL = QpH + (size_t)NTOT * MF;            // N*M us
    unsigned short* KVFh = (unsigned short*)A;                // B*M*DV us (A dead after kv)
    unsigned short* KVFl = KVFh + (size_t)NB * MF * DVV;      // B*M*DV us

    omsplit_kernel<<<DQK, 256, 0, stream>>>(omega, OmFh, OmFl);
    phi_kernel<false><<<NTOT / 64, 256, 0, stream>>>(K, OmFh, OmFl, (const float*)nullptr,
                                                     A, (unsigned short*)nullptr, (unsigned short*)nullptr, rmaxA);
    segsexp_kernel<<<NB, 256, 0, stream>>>(rmaxA, sexp);
    kv_kernel<<<dim3(2, 2, NB * 2), 256, 0, stream>>>(A, V, sexp, KV, P1, Ksum, KsumP);
    kvsplit_kernel<<<dim3(16, NB), 256, 0, stream>>>(KV, P1, KVFh, KVFl, Ksum, KsumP);
    phi_kernel<true ><<<NTOT / 64, 256, 0, stream>>>(Q, OmFh, OmFl, Ksum,
                                                     (float*)nullptr, QpH, QpL, normv);
    out_kernel<<<dim3(2, 8, NB), 256, 0, stream>>>(QpH, QpL, KVFh, KVFl, normv, out);
}